// Round 3
// baseline (727.025 us; speedup 1.0000x reference)
//
#include <hip/hip_runtime.h>
#include <cmath>

constexpr int BB = 4;
constexpr int SS = 8192;
constexpr int DMODEL = 1024;
constexpr int NHEADS = 16;
constexpr int DHEAD = 64;
constexpr int MTOK = BB * SS; // 32768

typedef __attribute__((ext_vector_type(8))) short short8; // 8 bf16 in 4 VGPRs
typedef __attribute__((ext_vector_type(4))) float f32x4;

__device__ __forceinline__ unsigned short f2bf(float f) {
    unsigned u = __float_as_uint(f);
    u += 0x7FFF + ((u >> 16) & 1); // RNE
    return (unsigned short)(u >> 16);
}

// ---------------------------------------------------------------------------
// 256x256-tile, BK=64, 8-wave (2x4), 8-phase pipelined bf16 GEMM: C = A x B^T.
// A: M x K row-major bf16. B: N x K row-major bf16 (pre-transposed weights).
//
// LDS (128 KiB, DYNAMIC): [buf 0/1][ A | B ], each matrix 2 khalves x 256
// rows x 32 k (khalf-major so a half-stage is lane-linear for
// global_load_lds, and all 8 waves consume the same staged half per phase).
//
// Bank swizzle (r2 fix): rows are 64 B = 4 granules of 16 B, so for a
// ds_read_b128 the granule group is (4*fl + chunk) mod 8 = 4*(fl&1) + chunk.
// chunk = quad ^ ((fl>>1)&3) makes each 8-lane phase cover all 8 groups
// (r2's quad^(fl&3) collided fl with fl+4 -> 1.9e7 conflict cycles).
// Staging inverse: stored chunk (c&3) at row (c>>2) holds global chunk
// (c&3) ^ ((c>>3)&3)  [ == (row>>1)&3 ].
//
// Schedule per K-tile (4 phases; stage order A0,B0,A1,B1 of tile t+1):
//   p0: read A(kh0,lo)+B(kh0); stage A0(t+1); bar; lgkm0; prio1; 16 MFMA; prio0; bar
//   p1: read A(kh0,hi);        stage B0(t+1); bar; lgkm0; prio1; 16 MFMA; prio0;
//       vmcnt(4) [A1,B1(t) landed]; bar
//   p2: read A(kh1,lo)+B(kh1); stage A1(t+1); bar; ...; bar
//   p3: read A(kh1,hi);        stage B1(t+1); bar; ...;
//       vmcnt(4) [A0,B0(t+1) landed]; bar
// vmcnt never drains to 0 in the main loop: >=4 loads always in flight.
// ---------------------------------------------------------------------------
#define STAGE2(gbase, lbase)                                                          \
    do {                                                                              \
        __builtin_amdgcn_global_load_lds(                                             \
            (const __attribute__((address_space(1))) unsigned int*)((gbase) + o0),    \
            (__attribute__((address_space(3))) unsigned int*)((lbase) + d0), 16, 0, 0);\
        __builtin_amdgcn_global_load_lds(                                             \
            (const __attribute__((address_space(1))) unsigned int*)((gbase) + o1),    \
            (__attribute__((address_space(3))) unsigned int*)((lbase) + d1), 16, 0, 0);\
    } while (0)

template <int EPI>
__global__ __launch_bounds__(512, 2) void la_gemm256(
    const unsigned short* __restrict__ A, const unsigned short* __restrict__ B,
    float* __restrict__ Cf,
    unsigned short* __restrict__ Cq, unsigned short* __restrict__ Ck,
    unsigned short* __restrict__ Cv,
    const int N, const int K, const int GX)
{
    extern __shared__ __align__(16) unsigned short smem[]; // 128 KiB dynamic

    const int t = threadIdx.x;
    const int wave = t >> 6, lane = t & 63;
    const int wm = wave >> 2, wn = wave & 3; // 2 x 4 wave grid
    const int quad = lane >> 4, fl = lane & 15;

    // T1: bijective XCD swizzle (grid sizes are multiples of 8)
    const int nwg = (int)gridDim.x;
    const int cpx = nwg >> 3;
    const int id = ((int)blockIdx.x & 7) * cpx + ((int)blockIdx.x >> 3);
    const int bx = id % GX, by = id / GX;
    const int m0 = by * 256, n0 = bx * 256;

    const unsigned short* a_g = A + (size_t)m0 * K;
    const unsigned short* b_g = B + (size_t)n0 * K;

    // staging: thread handles linear 16B-chunks t and 512+t of each 1024-chunk
    // half; stored chunk (c&3) at row (c>>2) fetches global chunk (c&3)^((c>>3)&3)
    const int c0 = t, c1 = 512 + t;
    const size_t o0 = (size_t)(c0 >> 2) * K + (size_t)((((c0 & 3) ^ ((c0 >> 3) & 3))) << 3);
    const size_t o1 = (size_t)(c1 >> 2) * K + (size_t)((((c1 & 3) ^ ((c1 >> 3) & 3))) << 3);
    const int d0 = c0 * 8, d1 = c1 * 8;

    // fragment read offsets (elements, within one khalf block of 8192)
    const int qsc = (quad ^ ((fl >> 1) & 3)) << 3; // swizzled chunk, lane-const
    const int offA = (wm * 128 + fl) * 32 + qsc;   // +2048 for row-half1, +i*512
    const int offB = (wn * 64 + fl) * 32 + qsc;    // +j*512

    f32x4 acc[8][4];
#pragma unroll
    for (int i = 0; i < 8; ++i)
#pragma unroll
        for (int j = 0; j < 4; ++j) acc[i][j] = (f32x4){0.f, 0.f, 0.f, 0.f};

    unsigned short* bufc = smem;          // current: A @+0, B @+16384 (khalf +8192)
    unsigned short* bufn = smem + 32768;

    // prologue: fully stage tile 0 (order A0,B0,A1,B1), land A0+B0
    STAGE2(a_g,      bufc);
    STAGE2(b_g,      bufc + 16384);
    STAGE2(a_g + 32, bufc + 8192);
    STAGE2(b_g + 32, bufc + 24576);
    asm volatile("s_waitcnt vmcnt(4)" ::: "memory");
    __builtin_amdgcn_s_barrier();

    for (int kt = 0; kt < K - 64; kt += 64) {
        const unsigned short* an = a_g + kt + 64;
        const unsigned short* bn = b_g + kt + 64;
        short8 ah[4], bh[4];

        // ---- phase 0: khalf0, row-half0
#pragma unroll
        for (int i = 0; i < 4; ++i) ah[i] = *(const short8*)(bufc + offA + i * 512);
#pragma unroll
        for (int j = 0; j < 4; ++j) bh[j] = *(const short8*)(bufc + 16384 + offB + j * 512);
        STAGE2(an, bufn);
        __builtin_amdgcn_s_barrier();
        asm volatile("s_waitcnt lgkmcnt(0)" ::: "memory");
        __builtin_amdgcn_s_setprio(1);
#pragma unroll
        for (int i = 0; i < 4; ++i)
#pragma unroll
            for (int j = 0; j < 4; ++j)
                acc[i][j] = __builtin_amdgcn_mfma_f32_16x16x32_bf16(ah[i], bh[j], acc[i][j], 0, 0, 0);
        __builtin_amdgcn_s_setprio(0);
        __builtin_amdgcn_s_barrier();

        // ---- phase 1: khalf0, row-half1 (reuse bh)
#pragma unroll
        for (int i = 0; i < 4; ++i) ah[i] = *(const short8*)(bufc + offA + 2048 + i * 512);
        STAGE2(bn, bufn + 16384);
        __builtin_amdgcn_s_barrier();
        asm volatile("s_waitcnt lgkmcnt(0)" ::: "memory");
        __builtin_amdgcn_s_setprio(1);
#pragma unroll
        for (int i = 0; i < 4; ++i)
#pragma unroll
            for (int j = 0; j < 4; ++j)
                acc[4 + i][j] = __builtin_amdgcn_mfma_f32_16x16x32_bf16(ah[i], bh[j], acc[4 + i][j], 0, 0, 0);
        __builtin_amdgcn_s_setprio(0);
        asm volatile("s_waitcnt vmcnt(4)" ::: "memory"); // A1,B1 of tile t landed
        __builtin_amdgcn_s_barrier();

        // ---- phase 2: khalf1, row-half0
#pragma unroll
        for (int i = 0; i < 4; ++i) ah[i] = *(const short8*)(bufc + 8192 + offA + i * 512);
#pragma unroll
        for (int j = 0; j < 4; ++j) bh[j] = *(const short8*)(bufc + 24576 + offB + j * 512);
        STAGE2(an + 32, bufn + 8192);
        __builtin_amdgcn_s_barrier();
        asm volatile("s_waitcnt lgkmcnt(0)" ::: "memory");
        __builtin_amdgcn_s_setprio(1);
#pragma unroll
        for (int i = 0; i < 4; ++i)
#pragma unroll
            for (int j = 0; j < 4; ++j)
                acc[i][j] = __builtin_amdgcn_mfma_f32_16x16x32_bf16(ah[i], bh[j], acc[i][j], 0, 0, 0);
        __builtin_amdgcn_s_setprio(0);
        __builtin_amdgcn_s_barrier();

        // ---- phase 3: khalf1, row-half1 (reuse bh)
#pragma unroll
        for (int i = 0; i < 4; ++i) ah[i] = *(const short8*)(bufc + 8192 + offA + 2048 + i * 512);
        STAGE2(bn + 32, bufn + 24576);
        __builtin_amdgcn_s_barrier();
        asm volatile("s_waitcnt lgkmcnt(0)" ::: "memory");
        __builtin_amdgcn_s_setprio(1);
#pragma unroll
        for (int i = 0; i < 4; ++i)
#pragma unroll
            for (int j = 0; j < 4; ++j)
                acc[4 + i][j] = __builtin_amdgcn_mfma_f32_16x16x32_bf16(ah[i], bh[j], acc[4 + i][j], 0, 0, 0);
        __builtin_amdgcn_s_setprio(0);
        asm volatile("s_waitcnt vmcnt(4)" ::: "memory"); // A0,B0 of tile t+1 landed
        __builtin_amdgcn_s_barrier();

        unsigned short* tmp = bufc; bufc = bufn; bufn = tmp;
    }

    // ---- peeled last tile (no staging; drain remaining A1,B1 before khalf1)
    {
        short8 ah[4], bh[4];
#pragma unroll
        for (int i = 0; i < 4; ++i) ah[i] = *(const short8*)(bufc + offA + i * 512);
#pragma unroll
        for (int j = 0; j < 4; ++j) bh[j] = *(const short8*)(bufc + 16384 + offB + j * 512);
#pragma unroll
        for (int i = 0; i < 4; ++i)
#pragma unroll
            for (int j = 0; j < 4; ++j)
                acc[i][j] = __builtin_amdgcn_mfma_f32_16x16x32_bf16(ah[i], bh[j], acc[i][j], 0, 0, 0);
#pragma unroll
        for (int i = 0; i < 4; ++i) ah[i] = *(const short8*)(bufc + offA + 2048 + i * 512);
#pragma unroll
        for (int i = 0; i < 4; ++i)
#pragma unroll
            for (int j = 0; j < 4; ++j)
                acc[4 + i][j] = __builtin_amdgcn_mfma_f32_16x16x32_bf16(ah[i], bh[j], acc[4 + i][j], 0, 0, 0);
        asm volatile("s_waitcnt vmcnt(0)" ::: "memory");
        __builtin_amdgcn_s_barrier();
#pragma unroll
        for (int i = 0; i < 4; ++i) ah[i] = *(const short8*)(bufc + 8192 + offA + i * 512);
#pragma unroll
        for (int j = 0; j < 4; ++j) bh[j] = *(const short8*)(bufc + 24576 + offB + j * 512);
#pragma unroll
        for (int i = 0; i < 4; ++i)
#pragma unroll
            for (int j = 0; j < 4; ++j)
                acc[i][j] = __builtin_amdgcn_mfma_f32_16x16x32_bf16(ah[i], bh[j], acc[i][j], 0, 0, 0);
#pragma unroll
        for (int i = 0; i < 4; ++i) ah[i] = *(const short8*)(bufc + 8192 + offA + 2048 + i * 512);
#pragma unroll
        for (int i = 0; i < 4; ++i)
#pragma unroll
            for (int j = 0; j < 4; ++j)
                acc[4 + i][j] = __builtin_amdgcn_mfma_f32_16x16x32_bf16(ah[i], bh[j], acc[4 + i][j], 0, 0, 0);
    }

    // C/D layout (m89-verified): col = lane&15, row = (lane>>4)*4 + reg
    if (EPI == 1) {
        const int bsel = n0 >> 10; // 0:q 1:k 2:v (256 | 1024, never straddles)
        unsigned short* Cp = (bsel == 0) ? Cq : ((bsel == 1) ? Ck : Cv);
        const bool act = (bsel < 2);
        const int colb = (n0 & 1023) + wn * 64 + fl;
#pragma unroll
        for (int i = 0; i < 8; ++i) {
            const int rowb = m0 + wm * 128 + i * 16 + quad * 4;
#pragma unroll
            for (int j = 0; j < 4; ++j) {
                const int col = colb + j * 16;
#pragma unroll
                for (int r = 0; r < 4; ++r) {
                    float v = acc[i][j][r];
                    if (act) v = (v > 0.f) ? v + 1.f : __expf(v);
                    Cp[(size_t)(rowb + r) * 1024 + col] = f2bf(v);
                }
            }
        }
    } else {
#pragma unroll
        for (int i = 0; i < 8; ++i) {
            const int rowb = m0 + wm * 128 + i * 16 + quad * 4;
#pragma unroll
            for (int j = 0; j < 4; ++j) {
                const int col = n0 + wn * 64 + fl + j * 16;
#pragma unroll
                for (int r = 0; r < 4; ++r)
                    Cf[(size_t)(rowb + r) * N + col] = acc[i][j][r];
            }
        }
    }
}

// ---------------------------------------------------------------------------
// fp32 -> bf16 cast, elementwise (for x)
// ---------------------------------------------------------------------------
__global__ __launch_bounds__(256) void cast_bf16(
    const float4* __restrict__ in, ushort4* __restrict__ hi, int n4)
{
    int i = blockIdx.x * 256 + threadIdx.x;
    const int stride = gridDim.x * 256;
    for (; i < n4; i += stride) {
        const float4 v = in[i];
        ushort4 h;
        h.x = f2bf(v.x); h.y = f2bf(v.y); h.z = f2bf(v.z); h.w = f2bf(v.w);
        hi[i] = h;
    }
}

// ---------------------------------------------------------------------------
// fp32 K x N -> bf16 N x K (transposed cast, for weights)
// ---------------------------------------------------------------------------
__global__ __launch_bounds__(256) void cast_T(
    const float* __restrict__ w, unsigned short* __restrict__ hiT, int Kd, int Nd)
{
    __shared__ float tile[32][33];
    const int t = threadIdx.x;
    const int n0 = blockIdx.x * 32, k0 = blockIdx.y * 32;
    const int r = t >> 3, c4 = (t & 7) * 4;
    const float4 v = *(const float4*)(w + (size_t)(k0 + r) * Nd + n0 + c4);
    tile[r][c4 + 0] = v.x; tile[r][c4 + 1] = v.y;
    tile[r][c4 + 2] = v.z; tile[r][c4 + 3] = v.w;
    __syncthreads();
    ushort4 h;
    h.x = f2bf(tile[c4 + 0][r]); h.y = f2bf(tile[c4 + 1][r]);
    h.z = f2bf(tile[c4 + 2][r]); h.w = f2bf(tile[c4 + 3][r]);
    *(ushort4*)(hiT + (size_t)(n0 + r) * Kd + k0 + c4) = h;
}

// ---------------------------------------------------------------------------
// kv[b,h,d,f] = sum_s k[s,d]*v[s,f];  ksum[b,h,d] = sum_s k.  (bf16 in, fp32 out)
// ---------------------------------------------------------------------------
constexpr int KV_CHUNKS = 16;

__global__ __launch_bounds__(256) void la_kvsum(
    const unsigned short* __restrict__ Kb, const unsigned short* __restrict__ Vb,
    float* __restrict__ kv, float* __restrict__ ksum)
{
    __shared__ float kk[32][68];
    __shared__ float vv[32][68];
    const int t = threadIdx.x;
    const int bh = blockIdx.x;
    const int b = bh >> 4, h = bh & 15;
    const int r = t >> 3, c8 = (t & 7) * 8;
    const int d0 = (t & 15) * 4, f0 = (t >> 4) * 4;
    float acc[4][4];
#pragma unroll
    for (int i = 0; i < 4; ++i)
#pragma unroll
        for (int j = 0; j < 4; ++j) acc[i][j] = 0.f;
    float ks = 0.f;
    const int s0 = blockIdx.y * (SS / KV_CHUNKS);

    for (int st = 0; st < SS / KV_CHUNKS; st += 32) {
        const size_t row = (size_t)(b * SS + s0 + st + r) * DMODEL + h * DHEAD + c8;
        const uint4 ku = *(const uint4*)(Kb + row);  // 8 bf16
        const uint4 vu = *(const uint4*)(Vb + row);
        __syncthreads();
        const unsigned ka_[4] = {ku.x, ku.y, ku.z, ku.w};
        const unsigned va_[4] = {vu.x, vu.y, vu.z, vu.w};
#pragma unroll
        for (int e = 0; e < 4; ++e) {
            kk[r][c8 + 2 * e]     = __uint_as_float(ka_[e] << 16);
            kk[r][c8 + 2 * e + 1] = __uint_as_float(ka_[e] & 0xFFFF0000u);
            vv[r][c8 + 2 * e]     = __uint_as_float(va_[e] << 16);
            vv[r][c8 + 2 * e + 1] = __uint_as_float(va_[e] & 0xFFFF0000u);
        }
        __syncthreads();
#pragma unroll 8
        for (int rr = 0; rr < 32; ++rr) {
            float4 kr = *(const float4*)&kk[rr][d0];
            float4 vr = *(const float4*)&vv[rr][f0];
            float ka[4] = {kr.x, kr.y, kr.z, kr.w};
            float va[4] = {vr.x, vr.y, vr.z, vr.w};
#pragma unroll
            for (int i = 0; i < 4; ++i)
#pragma unroll
                for (int j = 0; j < 4; ++j)
                    acc[i][j] = fmaf(ka[i], va[j], acc[i][j]);
        }
        if (t < 64) {
#pragma unroll 8
            for (int rr = 0; rr < 32; ++rr) ks += kk[rr][t];
        }
    }

    float* kvp = kv + (size_t)bh * DHEAD * DHEAD;
#pragma unroll
    for (int i = 0; i < 4; ++i)
#pragma unroll
        for (int j = 0; j < 4; ++j)
            atomicAdd(&kvp[(d0 + i) * DHEAD + f0 + j], acc[i][j]);
    if (t < 64) atomicAdd(&ksum[bh * DHEAD + t], ks);
}

// ---------------------------------------------------------------------------
// attn = (q.kv)/(q.ksum+1e-6), LDS-tiled: block = 64 tokens, loop 16 heads.
// ---------------------------------------------------------------------------
__global__ __launch_bounds__(256) void la_attn(
    const unsigned short* __restrict__ Q, const float* __restrict__ kv,
    const float* __restrict__ ksum, unsigned short* __restrict__ attn)
{
    __shared__ float kvs[64][68];
    __shared__ float qs[64][68];
    __shared__ float kss[64];
    const int t = threadIdx.x;
    const int t0 = blockIdx.x * 64;
    const int b = t0 / SS;
    const int tok_g = t >> 4;
    const int f_g = t & 15;

    for (int hh = 0; hh < NHEADS; ++hh) {
        __syncthreads();
        const float* kvp = kv + (size_t)(b * NHEADS + hh) * DHEAD * DHEAD;
#pragma unroll
        for (int i = 0; i < 4; ++i) {
            const int idx = i * 256 + t;
            const int r = idx >> 4, c4 = (idx & 15) * 4;
            *(float4*)&kvs[r][c4] = *(const float4*)(kvp + r * 64 + c4);
        }
        if (t < 64) kss[t] = ksum[(b * NHEADS + hh) * DHEAD + t];
#pragma unroll
        for (int i = 0; i < 2; ++i) {
            const int idx = i * 256 + t;
            const int r = idx >> 3, c8 = (idx & 7) * 8;
            const uint4 qu = *(const uint4*)(Q + (size_t)(t0 + r) * DMODEL + hh * 64 + c8);
            const unsigned a[4] = {qu.x, qu.y, qu.z, qu.w};
#pragma unroll
            for (int e = 0; e < 4; ++e) {
                qs[r][c8 + 2 * e]     = __uint_as_float(a[e] << 16);
                qs[r][c8 + 2 * e + 1] = __uint_as_float(a[e] & 0xFFFF0000u);
            }
        }
        __syncthreads();

        float acc[4][4];
        float den[4];
#pragma unroll
        for (int i = 0; i < 4; ++i) {
            den[i] = 0.f;
#pragma unroll
            for (int j = 0; j < 4; ++j) acc[i][j] = 0.f;
        }
#pragma unroll 8
        for (int d = 0; d < 64; ++d) {
            const float4 kvf = *(const float4*)&kvs[d][f_g * 4];
            const float ks = kss[d];
#pragma unroll
            for (int i = 0; i < 4; ++i) {
                const float qd = qs[tok_g * 4 + i][d];
                den[i]    = fmaf(qd, ks,    den[i]);
                acc[i][0] = fmaf(qd, kvf.x, acc[i][0]);
                acc[i][1] = fmaf(qd, kvf.y, acc[i][1]);
                acc[i][2] = fmaf(qd, kvf.z, acc[i][2]);
                acc[i][3] = fmaf(qd, kvf.w, acc[i][3]);
            }
        }
#pragma unroll
        for (int i = 0; i < 4; ++i) {
            const float rcp = 1.f / (den[i] + 1e-6f);
            ushort4 o;
            o.x = f2bf(acc[i][0] * rcp); o.y = f2bf(acc[i][1] * rcp);
            o.z = f2bf(acc[i][2] * rcp); o.w = f2bf(acc[i][3] * rcp);
            *(ushort4*)(attn + (size_t)(t0 + tok_g * 4 + i) * DMODEL + hh * 64 + f_g * 4) = o;
        }
    }
}

// sentinel: unmistakable marker if workspace is too small
__global__ void la_sentinel(float* out, int n) {
    int i = blockIdx.x * 256 + threadIdx.x;
    if (i < n) out[i] = 12345.0f;
}

// ---------------------------------------------------------------------------
extern "C" void kernel_launch(void* const* d_in, const int* in_sizes, int n_in,
                              void* d_out, int out_size, void* d_ws, size_t ws_size,
                              hipStream_t stream)
{
    const float* x     = (const float*)d_in[0];  // (B,S,1024)
    const float* w_qkv = (const float*)d_in[1];  // (1024,3072)
    const float* w_o   = (const float*)d_in[2];  // (1024,1024)
    float* out = (float*)d_out;

    // one-time: allow 128 KiB dynamic LDS for the GEMM kernels
    static bool attr_done = []() {
        hipFuncSetAttribute((const void*)&la_gemm256<1>,
                            hipFuncAttributeMaxDynamicSharedMemorySize, 131072);
        hipFuncSetAttribute((const void*)&la_gemm256<0>,
                            hipFuncAttributeMaxDynamicSharedMemorySize, 131072);
        return true;
    }();
    (void)attr_done;

    char* p = (char*)d_ws;
    const size_t x_bf = (size_t)MTOK * DMODEL * 2;          // 67.1 MB each
    unsigned short* x_hi = (unsigned short*)p; p += x_bf;   // reused as attn out
    unsigned short* wqT = (unsigned short*)p; p += (size_t)3 * DMODEL * DMODEL * 2;
    unsigned short* woT = (unsigned short*)p; p += (size_t)DMODEL * DMODEL * 2;
    unsigned short* q_buf = (unsigned short*)p; p += x_bf;  // bf16 q/k/v
    unsigned short* k_buf = (unsigned short*)p; p += x_bf;
    unsigned short* v_buf = (unsigned short*)p; p += x_bf;
    float* kvb = (float*)p; p += (size_t)BB * NHEADS * DHEAD * DHEAD * 4;
    float* ksb = (float*)p; p += (size_t)BB * NHEADS * DHEAD * 4;

    if ((size_t)(p - (char*)d_ws) > ws_size) {
        la_sentinel<<<(MTOK * DMODEL + 255) / 256, 256, 0, stream>>>(out, MTOK * DMODEL);
        return;
    }

    hipMemsetAsync(kvb, 0,
                   (size_t)(BB * NHEADS * DHEAD * DHEAD + BB * NHEADS * DHEAD) * sizeof(float),
                   stream);

    // 0) casts
    cast_bf16<<<8192, 256, 0, stream>>>((const float4*)x, (ushort4*)x_hi,
                                        MTOK * DMODEL / 4);
    cast_T<<<dim3(3 * DMODEL / 32, DMODEL / 32), 256, 0, stream>>>(w_qkv, wqT,
                                                                   DMODEL, 3 * DMODEL);
    cast_T<<<dim3(DMODEL / 32, DMODEL / 32), 256, 0, stream>>>(w_o, woT,
                                                               DMODEL, DMODEL);

    // 1) qkv GEMM (elu+1 fused on q,k), bf16 outputs. grid 12x128 = 1536 (1D)
    la_gemm256<1><<<(3 * DMODEL / 256) * (MTOK / 256), 512, 131072, stream>>>(
        x_hi, wqT, nullptr, q_buf, k_buf, v_buf, 3 * DMODEL, DMODEL, 3 * DMODEL / 256);

    // 2) kv / ksum reduction (bf16 in, fp32 out)
    la_kvsum<<<dim3(BB * NHEADS, KV_CHUNKS), 256, 0, stream>>>(k_buf, v_buf, kvb, ksb);

    // 3) attn -> bf16 (reuses x_hi; x is dead after qkv GEMM)
    la_attn<<<MTOK / 64, 256, 0, stream>>>(q_buf, kvb, ksb, x_hi);

    // 4) out = attn @ w_o (fp32 out). grid 4x128 = 512 (1D)
    la_gemm256<0><<<(DMODEL / 256) * (MTOK / 256), 512, 131072, stream>>>(
        x_hi, woT, out, nullptr, nullptr, nullptr, DMODEL, DMODEL, DMODEL / 256);
}

// Round 4
// 719.189 us; speedup vs baseline: 1.0109x; 1.0109x over previous
//
#include <hip/hip_runtime.h>
#include <cmath>

constexpr int BB = 4;
constexpr int SS = 8192;
constexpr int DMODEL = 1024;
constexpr int NHEADS = 16;
constexpr int DHEAD = 64;
constexpr int MTOK = BB * SS; // 32768

typedef __attribute__((ext_vector_type(8))) short short8; // 8 bf16 in 4 VGPRs
typedef __attribute__((ext_vector_type(4))) float f32x4;

__device__ __forceinline__ unsigned short f2bf(float f) {
    unsigned u = __float_as_uint(f);
    u += 0x7FFF + ((u >> 16) & 1); // RNE
    return (unsigned short)(u >> 16);
}

// ---------------------------------------------------------------------------
// 256x256-tile, BK=64, 8-wave (2x4), software-pipelined bf16 GEMM: C = A x B^T.
// A: M x K row-major bf16. B: N x K row-major bf16 (pre-transposed weights).
//
// LDS (128 KiB, DYNAMIC): [buf 0/1][ A | B ], each matrix 2 khalves x 256
// rows x 32 k. Bank swizzle (r3-verified, 0 conflicts): granule group for a
// ds_read_b128 is 4*(fl&1) + chunk; chunk = quad ^ ((fl>>1)&3) covers all 8
// groups per 8-lane phase. Staging inverse: stored chunk (c&3) at row (c>>2)
// holds global chunk (c&3) ^ ((c>>3)&3).
//
// r4 change (fix phase serialization, MfmaUtil 39%): fragment reads for phase
// p+1 are issued BEFORE MFMA(p) into alternate regs (ah0/ah1, bh0/bh1), so
// the LDS drain overlaps the matrix pipe. One barrier per phase (4/K-tile).
// Ledger: vmcnt(2) at ends of ph0/ph2 -> {A1,B1(t)} / {A0,B0(t+1)} landed
// >=1 phase before any wave ds_reads them (barrier + sched_barrier(0) after).
// Reads of buffer X_t lgkm-drain before MFMA(ph3), one barrier before X_t is
// re-staged at ph0(t+1). vmcnt never drains to 0 in the main loop.
// ---------------------------------------------------------------------------
#define STAGE2(gbase, lbase)                                                          \
    do {                                                                              \
        __builtin_amdgcn_global_load_lds(                                             \
            (const __attribute__((address_space(1))) unsigned int*)((gbase) + o0),    \
            (__attribute__((address_space(3))) unsigned int*)((lbase) + d0), 16, 0, 0);\
        __builtin_amdgcn_global_load_lds(                                             \
            (const __attribute__((address_space(1))) unsigned int*)((gbase) + o1),    \
            (__attribute__((address_space(3))) unsigned int*)((lbase) + d1), 16, 0, 0);\
    } while (0)

#define MFMA16(ACCROW, AH, BH)                                                        \
    do {                                                                              \
        __builtin_amdgcn_s_setprio(1);                                                \
        _Pragma("unroll")                                                             \
        for (int i = 0; i < 4; ++i)                                                   \
            _Pragma("unroll")                                                         \
            for (int j = 0; j < 4; ++j)                                               \
                acc[ACCROW + i][j] = __builtin_amdgcn_mfma_f32_16x16x32_bf16(         \
                    AH[i], BH[j], acc[ACCROW + i][j], 0, 0, 0);                       \
        __builtin_amdgcn_s_setprio(0);                                                \
    } while (0)

template <int EPI>
__global__ __launch_bounds__(512, 2) void la_gemm256(
    const unsigned short* __restrict__ A, const unsigned short* __restrict__ B,
    float* __restrict__ Cf,
    unsigned short* __restrict__ Cq, unsigned short* __restrict__ Ck,
    unsigned short* __restrict__ Cv,
    const int N, const int K, const int GX)
{
    extern __shared__ __align__(16) unsigned short smem[]; // 128 KiB dynamic

    const int t = threadIdx.x;
    const int wave = t >> 6, lane = t & 63;
    const int wm = wave >> 2, wn = wave & 3; // 2 x 4 wave grid
    const int quad = lane >> 4, fl = lane & 15;

    // T1: bijective XCD swizzle (grid sizes are multiples of 8)
    const int nwg = (int)gridDim.x;
    const int cpx = nwg >> 3;
    const int id = ((int)blockIdx.x & 7) * cpx + ((int)blockIdx.x >> 3);
    const int bx = id % GX, by = id / GX;
    const int m0 = by * 256, n0 = bx * 256;

    const unsigned short* a_g = A + (size_t)m0 * K;
    const unsigned short* b_g = B + (size_t)n0 * K;

    // staging: thread handles linear 16B-chunks t and 512+t of each 1024-chunk
    // half; stored chunk (c&3) at row (c>>2) fetches global chunk (c&3)^((c>>3)&3)
    const int c0 = t, c1 = 512 + t;
    const size_t o0 = (size_t)(c0 >> 2) * K + (size_t)((((c0 & 3) ^ ((c0 >> 3) & 3))) << 3);
    const size_t o1 = (size_t)(c1 >> 2) * K + (size_t)((((c1 & 3) ^ ((c1 >> 3) & 3))) << 3);
    const int d0 = c0 * 8, d1 = c1 * 8;

    // fragment read offsets (elements, within one khalf block of 8192)
    const int qsc = (quad ^ ((fl >> 1) & 3)) << 3; // swizzled chunk, lane-const
    const int offA = (wm * 128 + fl) * 32 + qsc;   // +2048 for row-half1, +i*512
    const int offB = (wn * 64 + fl) * 32 + qsc;    // +j*512

    f32x4 acc[8][4];
#pragma unroll
    for (int i = 0; i < 8; ++i)
#pragma unroll
        for (int j = 0; j < 4; ++j) acc[i][j] = (f32x4){0.f, 0.f, 0.f, 0.f};

    unsigned short* bufc = smem;          // current: A @+0, B @+16384 (khalf +8192)
    unsigned short* bufn = smem + 32768;

    // prologue: fully stage tile 0 (order A0,B0,A1,B1), land A0+B0, read ph0 frags
    STAGE2(a_g,      bufc);
    STAGE2(b_g,      bufc + 16384);
    STAGE2(a_g + 32, bufc + 8192);
    STAGE2(b_g + 32, bufc + 24576);
    asm volatile("s_waitcnt vmcnt(4)" ::: "memory");
    __builtin_amdgcn_s_barrier();
    __builtin_amdgcn_sched_barrier(0);

    short8 ah0[4], ah1[4], bh0[4], bh1[4];
#pragma unroll
    for (int i = 0; i < 4; ++i) ah0[i] = *(const short8*)(bufc + offA + i * 512);
#pragma unroll
    for (int j = 0; j < 4; ++j) bh0[j] = *(const short8*)(bufc + 16384 + offB + j * 512);

    for (int kt = 0; kt < K; kt += 64) {
        const int ktn = (kt + 64 < K) ? kt + 64 : kt; // clamp: last tile re-stages self
        const unsigned short* an = a_g + ktn;
        const unsigned short* bn = b_g + ktn;

        // ---- body 0: prefetch ah1<-A0hi ; stage A0(t+1) ; MFMA(kh0,lo)
#pragma unroll
        for (int i = 0; i < 4; ++i) ah1[i] = *(const short8*)(bufc + offA + 2048 + i * 512);
        STAGE2(an, bufn);
        MFMA16(0, ah0, bh0);
        asm volatile("s_waitcnt vmcnt(2)" ::: "memory"); // A1,B1(t) landed
        __builtin_amdgcn_s_barrier();
        __builtin_amdgcn_sched_barrier(0);

        // ---- body 1: prefetch ah0<-A1lo, bh1<-B1 ; stage B0(t+1) ; MFMA(kh0,hi)
#pragma unroll
        for (int i = 0; i < 4; ++i) ah0[i] = *(const short8*)(bufc + 8192 + offA + i * 512);
#pragma unroll
        for (int j = 0; j < 4; ++j) bh1[j] = *(const short8*)(bufc + 24576 + offB + j * 512);
        STAGE2(bn, bufn + 16384);
        MFMA16(4, ah1, bh0);
        __builtin_amdgcn_s_barrier();

        // ---- body 2: prefetch ah1<-A1hi ; stage A1(t+1) ; MFMA(kh1,lo)
#pragma unroll
        for (int i = 0; i < 4; ++i) ah1[i] = *(const short8*)(bufc + 8192 + offA + 2048 + i * 512);
        STAGE2(an + 32, bufn + 8192);
        MFMA16(0, ah0, bh1);
        asm volatile("s_waitcnt vmcnt(2)" ::: "memory"); // A0,B0(t+1) landed
        __builtin_amdgcn_s_barrier();
        __builtin_amdgcn_sched_barrier(0);

        // ---- body 3: prefetch ah0<-A0lo(t+1), bh0<-B0(t+1) ; stage B1(t+1) ; MFMA(kh1,hi)
#pragma unroll
        for (int i = 0; i < 4; ++i) ah0[i] = *(const short8*)(bufn + offA + i * 512);
#pragma unroll
        for (int j = 0; j < 4; ++j) bh0[j] = *(const short8*)(bufn + 16384 + offB + j * 512);
        STAGE2(bn + 32, bufn + 24576);
        MFMA16(4, ah1, bh1);
        __builtin_amdgcn_s_barrier();

        unsigned short* tmp = bufc; bufc = bufn; bufn = tmp;
    }
    asm volatile("s_waitcnt vmcnt(0)" ::: "memory"); // drain stages before exit

    // C/D layout (m89-verified): col = lane&15, row = (lane>>4)*4 + reg
    if (EPI == 1) {
        const int bsel = n0 >> 10; // 0:q 1:k 2:v (256 | 1024, never straddles)
        unsigned short* Cp = (bsel == 0) ? Cq : ((bsel == 1) ? Ck : Cv);
        const bool act = (bsel < 2);
        const int colb = (n0 & 1023) + wn * 64 + fl;
#pragma unroll
        for (int i = 0; i < 8; ++i) {
            const int rowb = m0 + wm * 128 + i * 16 + quad * 4;
#pragma unroll
            for (int j = 0; j < 4; ++j) {
                const int col = colb + j * 16;
#pragma unroll
                for (int r = 0; r < 4; ++r) {
                    float v = acc[i][j][r];
                    if (act) v = (v > 0.f) ? v + 1.f : __expf(v);
                    Cp[(size_t)(rowb + r) * 1024 + col] = f2bf(v);
                }
            }
        }
    } else {
#pragma unroll
        for (int i = 0; i < 8; ++i) {
            const int rowb = m0 + wm * 128 + i * 16 + quad * 4;
#pragma unroll
            for (int j = 0; j < 4; ++j) {
                const int col = n0 + wn * 64 + fl + j * 16;
#pragma unroll
                for (int r = 0; r < 4; ++r)
                    Cf[(size_t)(rowb + r) * N + col] = acc[i][j][r];
            }
        }
    }
}

// ---------------------------------------------------------------------------
// fp32 -> bf16 cast, elementwise (for x)
// ---------------------------------------------------------------------------
__global__ __launch_bounds__(256) void cast_bf16(
    const float4* __restrict__ in, ushort4* __restrict__ hi, int n4)
{
    int i = blockIdx.x * 256 + threadIdx.x;
    const int stride = gridDim.x * 256;
    for (; i < n4; i += stride) {
        const float4 v = in[i];
        ushort4 h;
        h.x = f2bf(v.x); h.y = f2bf(v.y); h.z = f2bf(v.z); h.w = f2bf(v.w);
        hi[i] = h;
    }
}

// ---------------------------------------------------------------------------
// fp32 K x N -> bf16 N x K (transposed cast, for weights)
// ---------------------------------------------------------------------------
__global__ __launch_bounds__(256) void cast_T(
    const float* __restrict__ w, unsigned short* __restrict__ hiT, int Kd, int Nd)
{
    __shared__ float tile[32][33];
    const int t = threadIdx.x;
    const int n0 = blockIdx.x * 32, k0 = blockIdx.y * 32;
    const int r = t >> 3, c4 = (t & 7) * 4;
    const float4 v = *(const float4*)(w + (size_t)(k0 + r) * Nd + n0 + c4);
    tile[r][c4 + 0] = v.x; tile[r][c4 + 1] = v.y;
    tile[r][c4 + 2] = v.z; tile[r][c4 + 3] = v.w;
    __syncthreads();
    ushort4 h;
    h.x = f2bf(tile[c4 + 0][r]); h.y = f2bf(tile[c4 + 1][r]);
    h.z = f2bf(tile[c4 + 2][r]); h.w = f2bf(tile[c4 + 3][r]);
    *(ushort4*)(hiT + (size_t)(n0 + r) * Kd + k0 + c4) = h;
}

// ---------------------------------------------------------------------------
// kv[b,h,d,f] = sum_s k[s,d]*v[s,f];  ksum[b,h,d] = sum_s k.  (bf16 in, fp32 out)
// ---------------------------------------------------------------------------
constexpr int KV_CHUNKS = 16;

__global__ __launch_bounds__(256) void la_kvsum(
    const unsigned short* __restrict__ Kb, const unsigned short* __restrict__ Vb,
    float* __restrict__ kv, float* __restrict__ ksum)
{
    __shared__ float kk[32][68];
    __shared__ float vv[32][68];
    const int t = threadIdx.x;
    const int bh = blockIdx.x;
    const int b = bh >> 4, h = bh & 15;
    const int r = t >> 3, c8 = (t & 7) * 8;
    const int d0 = (t & 15) * 4, f0 = (t >> 4) * 4;
    float acc[4][4];
#pragma unroll
    for (int i = 0; i < 4; ++i)
#pragma unroll
        for (int j = 0; j < 4; ++j) acc[i][j] = 0.f;
    float ks = 0.f;
    const int s0 = blockIdx.y * (SS / KV_CHUNKS);

    for (int st = 0; st < SS / KV_CHUNKS; st += 32) {
        const size_t row = (size_t)(b * SS + s0 + st + r) * DMODEL + h * DHEAD + c8;
        const uint4 ku = *(const uint4*)(Kb + row);  // 8 bf16
        const uint4 vu = *(const uint4*)(Vb + row);
        __syncthreads();
        const unsigned ka_[4] = {ku.x, ku.y, ku.z, ku.w};
        const unsigned va_[4] = {vu.x, vu.y, vu.z, vu.w};
#pragma unroll
        for (int e = 0; e < 4; ++e) {
            kk[r][c8 + 2 * e]     = __uint_as_float(ka_[e] << 16);
            kk[r][c8 + 2 * e + 1] = __uint_as_float(ka_[e] & 0xFFFF0000u);
            vv[r][c8 + 2 * e]     = __uint_as_float(va_[e] << 16);
            vv[r][c8 + 2 * e + 1] = __uint_as_float(va_[e] & 0xFFFF0000u);
        }
        __syncthreads();
#pragma unroll 8
        for (int rr = 0; rr < 32; ++rr) {
            float4 kr = *(const float4*)&kk[rr][d0];
            float4 vr = *(const float4*)&vv[rr][f0];
            float ka[4] = {kr.x, kr.y, kr.z, kr.w};
            float va[4] = {vr.x, vr.y, vr.z, vr.w};
#pragma unroll
            for (int i = 0; i < 4; ++i)
#pragma unroll
                for (int j = 0; j < 4; ++j)
                    acc[i][j] = fmaf(ka[i], va[j], acc[i][j]);
        }
        if (t < 64) {
#pragma unroll 8
            for (int rr = 0; rr < 32; ++rr) ks += kk[rr][t];
        }
    }

    float* kvp = kv + (size_t)bh * DHEAD * DHEAD;
#pragma unroll
    for (int i = 0; i < 4; ++i)
#pragma unroll
        for (int j = 0; j < 4; ++j)
            atomicAdd(&kvp[(d0 + i) * DHEAD + f0 + j], acc[i][j]);
    if (t < 64) atomicAdd(&ksum[bh * DHEAD + t], ks);
}

// ---------------------------------------------------------------------------
// attn = (q.kv)/(q.ksum+1e-6), LDS-tiled: block = 64 tokens, loop 16 heads.
// ---------------------------------------------------------------------------
__global__ __launch_bounds__(256) void la_attn(
    const unsigned short* __restrict__ Q, const float* __restrict__ kv,
    const float* __restrict__ ksum, unsigned short* __restrict__ attn)
{
    __shared__ float kvs[64][68];
    __shared__ float qs[64][68];
    __shared__ float kss[64];
    const int t = threadIdx.x;
    const int t0 = blockIdx.x * 64;
    const int b = t0 / SS;
    const int tok_g = t >> 4;
    const int f_g = t & 15;

    for (int hh = 0; hh < NHEADS; ++hh) {
        __syncthreads();
        const float* kvp = kv + (size_t)(b * NHEADS + hh) * DHEAD * DHEAD;
#pragma unroll
        for (int i = 0; i < 4; ++i) {
            const int idx = i * 256 + t;
            const int r = idx >> 4, c4 = (idx & 15) * 4;
            *(float4*)&kvs[r][c4] = *(const float4*)(kvp + r * 64 + c4);
        }
        if (t < 64) kss[t] = ksum[(b * NHEADS + hh) * DHEAD + t];
#pragma unroll
        for (int i = 0; i < 2; ++i) {
            const int idx = i * 256 + t;
            const int r = idx >> 3, c8 = (idx & 7) * 8;
            const uint4 qu = *(const uint4*)(Q + (size_t)(t0 + r) * DMODEL + hh * 64 + c8);
            const unsigned a[4] = {qu.x, qu.y, qu.z, qu.w};
#pragma unroll
            for (int e = 0; e < 4; ++e) {
                qs[r][c8 + 2 * e]     = __uint_as_float(a[e] << 16);
                qs[r][c8 + 2 * e + 1] = __uint_as_float(a[e] & 0xFFFF0000u);
            }
        }
        __syncthreads();

        float acc[4][4];
        float den[4];
#pragma unroll
        for (int i = 0; i < 4; ++i) {
            den[i] = 0.f;
#pragma unroll
            for (int j = 0; j < 4; ++j) acc[i][j] = 0.f;
        }
#pragma unroll 8
        for (int d = 0; d < 64; ++d) {
            const float4 kvf = *(const float4*)&kvs[d][f_g * 4];
            const float ks = kss[d];
#pragma unroll
            for (int i = 0; i < 4; ++i) {
                const float qd = qs[tok_g * 4 + i][d];
                den[i]    = fmaf(qd, ks,    den[i]);
                acc[i][0] = fmaf(qd, kvf.x, acc[i][0]);
                acc[i][1] = fmaf(qd, kvf.y, acc[i][1]);
                acc[i][2] = fmaf(qd, kvf.z, acc[i][2]);
                acc[i][3] = fmaf(qd, kvf.w, acc[i][3]);
            }
        }
#pragma unroll
        for (int i = 0; i < 4; ++i) {
            const float rcp = 1.f / (den[i] + 1e-6f);
            ushort4 o;
            o.x = f2bf(acc[i][0] * rcp); o.y = f2bf(acc[i][1] * rcp);
            o.z = f2bf(acc[i][2] * rcp); o.w = f2bf(acc[i][3] * rcp);
            *(ushort4*)(attn + (size_t)(t0 + tok_g * 4 + i) * DMODEL + hh * 64 + f_g * 4) = o;
        }
    }
}

// sentinel: unmistakable marker if workspace is too small
__global__ void la_sentinel(float* out, int n) {
    int i = blockIdx.x * 256 + threadIdx.x;
    if (i < n) out[i] = 12345.0f;
}

// ---------------------------------------------------------------------------
extern "C" void kernel_launch(void* const* d_in, const int* in_sizes, int n_in,
                              void* d_out, int out_size, void* d_ws, size_t ws_size,
                              hipStream_t stream)
{
    const float* x     = (const float*)d_in[0];  // (B,S,1024)
    const float* w_qkv = (const float*)d_in[1];  // (1024,3072)
    const float* w_o   = (const float*)d_in[2];  // (1024,1024)
    float* out = (float*)d_out;

    // one-time: allow 128 KiB dynamic LDS for the GEMM kernels
    static bool attr_done = []() {
        hipFuncSetAttribute((const void*)&la_gemm256<1>,
                            hipFuncAttributeMaxDynamicSharedMemorySize, 131072);
        hipFuncSetAttribute((const void*)&la_gemm256<0>,
                            hipFuncAttributeMaxDynamicSharedMemorySize, 131072);
        return true;
    }();
    (void)attr_done;

    char* p = (char*)d_ws;
    const size_t x_bf = (size_t)MTOK * DMODEL * 2;          // 67.1 MB each
    unsigned short* x_hi = (unsigned short*)p; p += x_bf;   // reused as attn out
    unsigned short* wqT = (unsigned short*)p; p += (size_t)3 * DMODEL * DMODEL * 2;
    unsigned short* woT = (unsigned short*)p; p += (size_t)DMODEL * DMODEL * 2;
    unsigned short* q_buf = (unsigned short*)p; p += x_bf;  // bf16 q/k/v
    unsigned short* k_buf = (unsigned short*)p; p += x_bf;
    unsigned short* v_buf = (unsigned short*)p; p += x_bf;
    float* kvb = (float*)p; p += (size_t)BB * NHEADS * DHEAD * DHEAD * 4;
    float* ksb = (float*)p; p += (size_t)BB * NHEADS * DHEAD * 4;

    if ((size_t)(p - (char*)d_ws) > ws_size) {
        la_sentinel<<<(MTOK * DMODEL + 255) / 256, 256, 0, stream>>>(out, MTOK * DMODEL);
        return;
    }

    hipMemsetAsync(kvb, 0,
                   (size_t)(BB * NHEADS * DHEAD * DHEAD + BB * NHEADS * DHEAD) * sizeof(float),
                   stream);

    // 0) casts
    cast_bf16<<<8192, 256, 0, stream>>>((const float4*)x, (ushort4*)x_hi,
                                        MTOK * DMODEL / 4);
    cast_T<<<dim3(3 * DMODEL / 32, DMODEL / 32), 256, 0, stream>>>(w_qkv, wqT,
                                                                   DMODEL, 3 * DMODEL);
    cast_T<<<dim3(DMODEL / 32, DMODEL / 32), 256, 0, stream>>>(w_o, woT,
                                                               DMODEL, DMODEL);

    // 1) qkv GEMM (elu+1 fused on q,k), bf16 outputs. grid 12x128 = 1536 (1D)
    la_gemm256<1><<<(3 * DMODEL / 256) * (MTOK / 256), 512, 131072, stream>>>(
        x_hi, wqT, nullptr, q_buf, k_buf, v_buf, 3 * DMODEL, DMODEL, 3 * DMODEL / 256);

    // 2) kv / ksum reduction (bf16 in, fp32 out)
    la_kvsum<<<dim3(BB * NHEADS, KV_CHUNKS), 256, 0, stream>>>(k_buf, v_buf, kvb, ksb);

    // 3) attn -> bf16 (reuses x_hi; x is dead after qkv GEMM)
    la_attn<<<MTOK / 64, 256, 0, stream>>>(q_buf, kvb, ksb, x_hi);

    // 4) out = attn @ w_o (fp32 out). grid 4x128 = 512 (1D)
    la_gemm256<0><<<(DMODEL / 256) * (MTOK / 256), 512, 131072, stream>>>(
        x_hi, woT, out, nullptr, nullptr, nullptr, DMODEL, DMODEL, DMODEL / 256);
}